// Round 1
// baseline (1424.781 us; speedup 1.0000x reference)
//
#include <hip/hip_runtime.h>
#include <math.h>

#define N_AGENTS 8192
#define HIDDEN   256
#define MSG      128
#define KEYD     64

// ---------------- Kernel A: projections (messages, keys, queries) -------------
__global__ void proj_kernel(const float* __restrict__ h,
                            const float* __restrict__ Wm, const float* __restrict__ bm,
                            const float* __restrict__ Wk, const float* __restrict__ bk,
                            const float* __restrict__ Wq, const float* __restrict__ bq,
                            float* __restrict__ msg, float* __restrict__ keys,
                            float* __restrict__ qry)
{
    const int R = 16;
    __shared__ float hs[R][HIDDEN];
    int i0 = blockIdx.x * R;
    int t = threadIdx.x;  // 256

    for (int l = t; l < R * HIDDEN; l += 256) {
        int r = l >> 8, k = l & 255;
        hs[r][k] = h[(size_t)(i0 + r) * HIDDEN + k];
    }
    __syncthreads();

    int j = t;
    const float* Wp; int stride, col; float bias;
    if (j < 128)      { Wp = Wm; stride = 128; col = j;       bias = bm[col]; }
    else if (j < 192) { Wp = Wk; stride = 64;  col = j - 128; bias = bk[col]; }
    else              { Wp = Wq; stride = 64;  col = j - 192; bias = bq[col]; }

    float acc[R];
#pragma unroll
    for (int r = 0; r < R; r++) acc[r] = 0.f;

    for (int k = 0; k < HIDDEN; k++) {
        float w = Wp[(size_t)k * stride + col];
#pragma unroll
        for (int r = 0; r < R; r++) acc[r] += hs[r][k] * w;
    }

    if (j < 128) {
#pragma unroll
        for (int r = 0; r < R; r++) msg[(size_t)(i0 + r) * MSG + col] = acc[r] + bias;
    } else if (j < 192) {
#pragma unroll
        for (int r = 0; r < R; r++) keys[(size_t)(i0 + r) * KEYD + col] = acc[r] + bias;
    } else {
#pragma unroll
        for (int r = 0; r < R; r++) qry[(size_t)(i0 + r) * KEYD + col] = acc[r] + bias;
    }
}

// ---------------- Kernel B: scores -> exp (unnormalized) + row sums ----------
__global__ void score_kernel(const float* __restrict__ qry, const float* __restrict__ keys,
                             float* __restrict__ P, float* __restrict__ rowsum)
{
    __shared__ float Qs[64][65];
    __shared__ float Ks[64][65];
    int i0 = blockIdx.y * 64;
    int j0 = blockIdx.x * 64;
    int t = threadIdx.x;  // 256

    for (int l = t; l < 64 * 64; l += 256) {
        int r = l >> 6, k = l & 63;
        Qs[r][k] = qry[(size_t)(i0 + r) * KEYD + k];
        Ks[r][k] = keys[(size_t)(j0 + r) * KEYD + k];
    }
    __syncthreads();

    int r0 = (t >> 4) * 4;  // 4 rows per thread
    int c0 = (t & 15) * 4;  // 4 cols per thread
    float acc[4][4];
#pragma unroll
    for (int i = 0; i < 4; i++)
#pragma unroll
        for (int u = 0; u < 4; u++) acc[i][u] = 0.f;

    for (int k = 0; k < 64; k++) {
        float q[4], kk[4];
#pragma unroll
        for (int i = 0; i < 4; i++) { q[i] = Qs[r0 + i][k]; kk[i] = Ks[c0 + i][k]; }
#pragma unroll
        for (int i = 0; i < 4; i++)
#pragma unroll
            for (int u = 0; u < 4; u++) acc[i][u] += q[i] * kk[u];
    }

    const float scale = 0.125f;  // 1/sqrt(64)
    float ps[4];
#pragma unroll
    for (int i = 0; i < 4; i++) ps[i] = 0.f;

#pragma unroll
    for (int i = 0; i < 4; i++) {
        float4 v;
        int gi = i0 + r0 + i;
#pragma unroll
        for (int u = 0; u < 4; u++) {
            float s = acc[i][u] * scale;
            s = fminf(fmaxf(s, -20.f), 20.f);
            int gj = j0 + c0 + u;
            float p = (gi == gj) ? 0.f : __expf(s);
            (&v.x)[u] = p;
            ps[i] += p;
        }
        *(float4*)&P[(size_t)gi * N_AGENTS + j0 + c0] = v;
    }

    // reduce across the 16 lanes (t&15) that share the same rows
#pragma unroll
    for (int off = 1; off < 16; off <<= 1) {
#pragma unroll
        for (int i = 0; i < 4; i++) ps[i] += __shfl_xor(ps[i], off);
    }
    if ((t & 15) == 0) {
#pragma unroll
        for (int i = 0; i < 4; i++) atomicAdd(&rowsum[i0 + r0 + i], ps[i]);
    }
}

// ------- Kernel C: normalize attn in place + attended = attn @ messages ------
__global__ void attend_kernel(const float* __restrict__ msg, const float* __restrict__ rowsum,
                              float* __restrict__ P, float* __restrict__ att)
{
    const int KT = 32;
    __shared__ float As[64][KT + 1];
    __shared__ float Bs[KT][MSG];
    __shared__ float inv[64];

    int i0 = blockIdx.y * 64;
    int kbase = blockIdx.x * 2048;   // K split by 4
    int t = threadIdx.x;  // 256

    if (t < 64) inv[t] = 1.0f / rowsum[i0 + t];
    __syncthreads();

    int r0 = (t >> 4) * 4;  // 4 rows
    int c0 = (t & 15) * 8;  // 8 cols
    float acc[4][8];
#pragma unroll
    for (int i = 0; i < 4; i++)
#pragma unroll
        for (int u = 0; u < 8; u++) acc[i][u] = 0.f;

    for (int k0 = kbase; k0 < kbase + 2048; k0 += KT) {
        __syncthreads();
        // load A tile (64 x KT), normalize, write back normalized attn
        for (int l = t; l < 64 * KT; l += 256) {
            int r = l >> 5, c = l & 31;
            size_t g = (size_t)(i0 + r) * N_AGENTS + k0 + c;
            float v = P[g] * inv[r];
            As[r][c] = v;
            P[g] = v;
        }
        // load B tile (KT x 128)
        for (int l = t; l < KT * MSG; l += 256) {
            int r = l >> 7, c = l & 127;
            Bs[r][c] = msg[(size_t)(k0 + r) * MSG + c];
        }
        __syncthreads();

        for (int kk = 0; kk < KT; kk++) {
            float a[4];
#pragma unroll
            for (int i = 0; i < 4; i++) a[i] = As[r0 + i][kk];
            float4 b0 = *(float4*)&Bs[kk][c0];
            float4 b1 = *(float4*)&Bs[kk][c0 + 4];
            float b[8] = {b0.x, b0.y, b0.z, b0.w, b1.x, b1.y, b1.z, b1.w};
#pragma unroll
            for (int i = 0; i < 4; i++)
#pragma unroll
                for (int u = 0; u < 8; u++) acc[i][u] += a[i] * b[u];
        }
    }

#pragma unroll
    for (int i = 0; i < 4; i++)
#pragma unroll
        for (int u = 0; u < 8; u++)
            atomicAdd(&att[(size_t)(i0 + r0 + i) * MSG + c0 + u], acc[i][u]);
}

// ---------------- Kernel D: GRU cell -----------------------------------------
__global__ void gru_kernel(const float* __restrict__ att, const float* __restrict__ h,
                           const float* __restrict__ Wir, const float* __restrict__ bir,
                           const float* __restrict__ Wiz, const float* __restrict__ biz,
                           const float* __restrict__ Win, const float* __restrict__ bin,
                           const float* __restrict__ Whr, const float* __restrict__ Whz,
                           const float* __restrict__ Whn, const float* __restrict__ bhn,
                           float* __restrict__ hnew)
{
    const int R = 16;
    __shared__ float as_[R][MSG];
    __shared__ float hs[R][HIDDEN];
    int i0 = blockIdx.x * R;
    int t = threadIdx.x;  // 256
    int j = t;

    for (int l = t; l < R * MSG; l += 256) {
        int r = l >> 7, c = l & 127;
        as_[r][c] = att[(size_t)(i0 + r) * MSG + c];
    }
    for (int l = t; l < R * HIDDEN; l += 256) {
        int r = l >> 8, c = l & 255;
        hs[r][c] = h[(size_t)(i0 + r) * HIDDEN + c];
    }
    __syncthreads();

    float ar[R], az[R], an[R], hn[R];
#pragma unroll
    for (int r = 0; r < R; r++) { ar[r] = 0.f; az[r] = 0.f; an[r] = 0.f; hn[r] = 0.f; }

    for (int k = 0; k < MSG; k++) {
        float wr = Wir[(size_t)k * HIDDEN + j];
        float wz = Wiz[(size_t)k * HIDDEN + j];
        float wn = Win[(size_t)k * HIDDEN + j];
#pragma unroll
        for (int r = 0; r < R; r++) {
            float a = as_[r][k];
            ar[r] += a * wr; az[r] += a * wz; an[r] += a * wn;
        }
    }
    for (int k = 0; k < HIDDEN; k++) {
        float wr = Whr[(size_t)k * HIDDEN + j];
        float wz = Whz[(size_t)k * HIDDEN + j];
        float wn = Whn[(size_t)k * HIDDEN + j];
#pragma unroll
        for (int r = 0; r < R; r++) {
            float hv = hs[r][k];
            ar[r] += hv * wr; az[r] += hv * wz; hn[r] += hv * wn;
        }
    }

    float br = bir[j], bz = biz[j], bn = bin[j], bh = bhn[j];
#pragma unroll
    for (int r = 0; r < R; r++) {
        float rr = 1.f / (1.f + __expf(-(ar[r] + br)));
        float zz = 1.f / (1.f + __expf(-(az[r] + bz)));
        float cand = tanhf(an[r] + bn + rr * (hn[r] + bh));
        hnew[(size_t)(i0 + r) * HIDDEN + j] = (1.f - zz) * cand + zz * hs[r][j];
    }
}

// ---------------- launch ------------------------------------------------------
extern "C" void kernel_launch(void* const* d_in, const int* in_sizes, int n_in,
                              void* d_out, int out_size, void* d_ws, size_t ws_size,
                              hipStream_t stream)
{
    const float* h    = (const float*)d_in[0];
    const float* W_msg = (const float*)d_in[1];
    const float* b_msg = (const float*)d_in[2];
    const float* W_key = (const float*)d_in[3];
    const float* b_key = (const float*)d_in[4];
    const float* W_qry = (const float*)d_in[5];
    const float* b_qry = (const float*)d_in[6];
    const float* Wi_r  = (const float*)d_in[7];
    const float* bi_r  = (const float*)d_in[8];
    const float* Wi_z  = (const float*)d_in[9];
    const float* bi_z  = (const float*)d_in[10];
    const float* Wi_n  = (const float*)d_in[11];
    const float* bi_n  = (const float*)d_in[12];
    const float* Wh_r  = (const float*)d_in[13];
    const float* Wh_z  = (const float*)d_in[14];
    const float* Wh_n  = (const float*)d_in[15];
    const float* bh_n  = (const float*)d_in[16];

    float* out  = (float*)d_out;
    float* hnew = out;                                   // [8192,256]
    float* P    = out + (size_t)N_AGENTS * HIDDEN;       // attn region [8192,8192]

    float* ws     = (float*)d_ws;
    float* rowsum = ws;                                  // 8192
    float* att    = ws + N_AGENTS;                       // 8192*128
    float* msg    = att + (size_t)N_AGENTS * MSG;        // 8192*128
    float* keys   = msg + (size_t)N_AGENTS * MSG;        // 8192*64
    float* qry    = keys + (size_t)N_AGENTS * KEYD;      // 8192*64

    // zero rowsum + attended accumulators
    hipMemsetAsync(d_ws, 0, (size_t)(N_AGENTS + N_AGENTS * MSG) * sizeof(float), stream);

    proj_kernel<<<N_AGENTS / 16, 256, 0, stream>>>(h, W_msg, b_msg, W_key, b_key,
                                                   W_qry, b_qry, msg, keys, qry);

    score_kernel<<<dim3(N_AGENTS / 64, N_AGENTS / 64), 256, 0, stream>>>(qry, keys, P, rowsum);

    attend_kernel<<<dim3(4, N_AGENTS / 64), 256, 0, stream>>>(msg, rowsum, P, att);

    gru_kernel<<<N_AGENTS / 16, 256, 0, stream>>>(att, h, Wi_r, bi_r, Wi_z, bi_z,
                                                  Wi_n, bi_n, Wh_r, Wh_z, Wh_n, bh_n, hnew);
}

// Round 2
// 718.425 us; speedup vs baseline: 1.9832x; 1.9832x over previous
//
#include <hip/hip_runtime.h>
#include <math.h>

#define N_AGENTS 8192
#define HIDDEN   256
#define MSG      128
#define KEYD     64
#define KSPLIT   8

typedef __attribute__((ext_vector_type(8))) short short8_t;
typedef __attribute__((ext_vector_type(4))) short short4_t;
typedef __attribute__((ext_vector_type(4))) float float4_t;

__device__ __forceinline__ short f2bf(float x) {
    unsigned u = __float_as_uint(x);
    unsigned r = (u + 0x7fffu + ((u >> 16) & 1u)) >> 16;
    return (short)r;
}
__device__ __forceinline__ float bf2f(short b) {
    return __uint_as_float(((unsigned)(unsigned short)b) << 16);
}

// ---------------- Kernel A: projections -> bf16 side buffers ------------------
// msgTb : [MSG][N] bf16 (transposed messages)
// qh/ql : [N][64] bf16 hi/lo split of queries
// kh/kl : [N][64] bf16 hi/lo split of keys
__global__ __launch_bounds__(256) void proj_kernel(
    const float* __restrict__ h,
    const float* __restrict__ Wm, const float* __restrict__ bm,
    const float* __restrict__ Wk, const float* __restrict__ bk,
    const float* __restrict__ Wq, const float* __restrict__ bq,
    short* __restrict__ msgTb,
    short* __restrict__ qh, short* __restrict__ ql,
    short* __restrict__ kh, short* __restrict__ kl)
{
    const int R = 16;
    __shared__ float hs[R][HIDDEN];
    int i0 = blockIdx.x * R;
    int t = threadIdx.x;  // 256

    for (int l = t; l < R * HIDDEN; l += 256) {
        int r = l >> 8, k = l & 255;
        hs[r][k] = h[(size_t)(i0 + r) * HIDDEN + k];
    }
    __syncthreads();

    int j = t;
    const float* Wp; int stride, col; float bias;
    if (j < 128)      { Wp = Wm; stride = 128; col = j;       bias = bm[col]; }
    else if (j < 192) { Wp = Wk; stride = 64;  col = j - 128; bias = bk[col]; }
    else              { Wp = Wq; stride = 64;  col = j - 192; bias = bq[col]; }

    float acc[R];
#pragma unroll
    for (int r = 0; r < R; r++) acc[r] = 0.f;

    for (int k = 0; k < HIDDEN; k++) {
        float w = Wp[(size_t)k * stride + col];
#pragma unroll
        for (int r = 0; r < R; r++) acc[r] += hs[r][k] * w;
    }

    if (j < 128) {
        // transposed bf16 messages: 16 consecutive n per thread
#pragma unroll
        for (int r = 0; r < R; r++)
            msgTb[(size_t)col * N_AGENTS + i0 + r] = f2bf(acc[r] + bias);
    } else if (j < 192) {
#pragma unroll
        for (int r = 0; r < R; r++) {
            float v = acc[r] + bias;
            short hi = f2bf(v);
            short lo = f2bf(v - bf2f(hi));
            kh[(size_t)(i0 + r) * KEYD + col] = hi;
            kl[(size_t)(i0 + r) * KEYD + col] = lo;
        }
    } else {
#pragma unroll
        for (int r = 0; r < R; r++) {
            float v = acc[r] + bias;
            short hi = f2bf(v);
            short lo = f2bf(v - bf2f(hi));
            qh[(size_t)(i0 + r) * KEYD + col] = hi;
            ql[(size_t)(i0 + r) * KEYD + col] = lo;
        }
    }
}

// ---------- Kernel B: MFMA scores -> exp (unnormalized P) + row sums ----------
// block = 256 threads (4 waves); block tile 64 rows x 256 cols; wave tile 64x64
__global__ __launch_bounds__(256) void score_kernel(
    const short* __restrict__ qh, const short* __restrict__ ql,
    const short* __restrict__ kh, const short* __restrict__ kl,
    float* __restrict__ P, float* __restrict__ rowsum)
{
    int t = threadIdx.x;
    int wave = t >> 6, l = t & 63;
    int quad = l >> 4, ln = l & 15;
    int i0 = blockIdx.y * 64;
    int j0 = blockIdx.x * 256 + wave * 64;

    // A fragments: rows i0 + r*16 + ln, k = ch*32 + quad*8 + j
    short8_t ah[4][2], al[4][2];
#pragma unroll
    for (int r = 0; r < 4; r++)
#pragma unroll
        for (int ch = 0; ch < 2; ch++) {
            size_t off = (size_t)(i0 + r * 16 + ln) * KEYD + ch * 32 + quad * 8;
            ah[r][ch] = *(const short8_t*)(qh + off);
            al[r][ch] = *(const short8_t*)(ql + off);
        }

    float4_t acc[4][4];
#pragma unroll
    for (int r = 0; r < 4; r++)
#pragma unroll
        for (int c = 0; c < 4; c++) acc[r][c] = (float4_t)0.f;

#pragma unroll
    for (int c = 0; c < 4; c++) {
        int coln = j0 + c * 16 + ln;
#pragma unroll
        for (int ch = 0; ch < 2; ch++) {
            size_t off = (size_t)coln * KEYD + ch * 32 + quad * 8;
            short8_t bh = *(const short8_t*)(kh + off);
            short8_t bl = *(const short8_t*)(kl + off);
#pragma unroll
            for (int r = 0; r < 4; r++) {
                acc[r][c] = __builtin_amdgcn_mfma_f32_16x16x32_bf16(ah[r][ch], bh, acc[r][c], 0, 0, 0);
                acc[r][c] = __builtin_amdgcn_mfma_f32_16x16x32_bf16(ah[r][ch], bl, acc[r][c], 0, 0, 0);
                acc[r][c] = __builtin_amdgcn_mfma_f32_16x16x32_bf16(al[r][ch], bh, acc[r][c], 0, 0, 0);
            }
        }
    }

    // epilogue: scale/clip/exp/diag-mask, write P, row-sum partials
    float prow[4][4];
#pragma unroll
    for (int r = 0; r < 4; r++)
#pragma unroll
        for (int reg = 0; reg < 4; reg++) {
            int gi = i0 + r * 16 + quad * 4 + reg;
            float sum = 0.f;
#pragma unroll
            for (int c = 0; c < 4; c++) {
                float s = acc[r][c][reg] * 0.125f;
                s = fminf(fmaxf(s, -20.f), 20.f);
                int gj = j0 + c * 16 + ln;
                float p = (gi == gj) ? 0.f : __expf(s);
                P[(size_t)gi * N_AGENTS + gj] = p;
                sum += p;
            }
            prow[r][reg] = sum;
        }

#pragma unroll
    for (int off = 1; off < 16; off <<= 1)
#pragma unroll
        for (int r = 0; r < 4; r++)
#pragma unroll
            for (int reg = 0; reg < 4; reg++)
                prow[r][reg] += __shfl_xor(prow[r][reg], off);

    if (ln == 0) {
#pragma unroll
        for (int r = 0; r < 4; r++)
#pragma unroll
            for (int reg = 0; reg < 4; reg++)
                atomicAdd(&rowsum[i0 + r * 16 + quad * 4 + reg], prow[r][reg]);
    }
}

// ------ Kernel C: normalize P in place (fp32) + attended = P @ msg (MFMA) -----
// grid (KSPLIT, N/64); block 256 = 4 waves; wave: 16 rows x 128 cols
__global__ __launch_bounds__(256) void attend_kernel(
    const short* __restrict__ msgTb, const float* __restrict__ rowsum,
    float* __restrict__ P, float* __restrict__ att)
{
    __shared__ short A_lds[64][72];
    __shared__ short B_lds[128][72];
    __shared__ float inv[64];

    int t = threadIdx.x;
    int wave = t >> 6, l = t & 63;
    int quad = l >> 4, ln = l & 15;
    int i0 = blockIdx.y * 64;
    int kbase = blockIdx.x * (N_AGENTS / KSPLIT);

    if (t < 64) inv[t] = 1.0f / rowsum[i0 + t];

    float4_t acc[8];
#pragma unroll
    for (int c = 0; c < 8; c++) acc[c] = (float4_t)0.f;

    for (int k0 = kbase; k0 < kbase + N_AGENTS / KSPLIT; k0 += 64) {
        __syncthreads();
        // stage A: P tile 64x64 fp32 -> normalize -> writeback -> bf16 LDS
#pragma unroll
        for (int p = 0; p < 4; p++) {
            int idx = t + p * 256;           // 0..1023
            int r = idx >> 4, c4 = (idx & 15) * 4;
            size_t g = (size_t)(i0 + r) * N_AGENTS + k0 + c4;
            float4 v = *(const float4*)&P[g];
            float s = inv[r];
            v.x *= s; v.y *= s; v.z *= s; v.w *= s;
            *(float4*)&P[g] = v;
            short4_t b;
            b[0] = f2bf(v.x); b[1] = f2bf(v.y); b[2] = f2bf(v.z); b[3] = f2bf(v.w);
            *(short4_t*)&A_lds[r][c4] = b;
        }
        // stage B: msgT 128 cols x 64 k
#pragma unroll
        for (int p = 0; p < 4; p++) {
            int idx = t + p * 256;           // 0..1023
            int c = idx >> 3, kk = (idx & 7) * 8;
            *(short8_t*)&B_lds[c][kk] = *(const short8_t*)(msgTb + (size_t)c * N_AGENTS + k0 + kk);
        }
        __syncthreads();

#pragma unroll
        for (int ch = 0; ch < 2; ch++) {
            short8_t a = *(short8_t*)&A_lds[wave * 16 + ln][ch * 32 + quad * 8];
#pragma unroll
            for (int c = 0; c < 8; c++) {
                short8_t b = *(short8_t*)&B_lds[c * 16 + ln][ch * 32 + quad * 8];
                acc[c] = __builtin_amdgcn_mfma_f32_16x16x32_bf16(a, b, acc[c], 0, 0, 0);
            }
        }
    }

#pragma unroll
    for (int c = 0; c < 8; c++)
#pragma unroll
        for (int reg = 0; reg < 4; reg++) {
            int row = i0 + wave * 16 + quad * 4 + reg;
            int col = c * 16 + ln;
            atomicAdd(&att[(size_t)row * MSG + col], acc[c][reg]);
        }
}

// ---------------- Kernel D: GRU cell -----------------------------------------
__global__ __launch_bounds__(256) void gru_kernel(
    const float* __restrict__ att, const float* __restrict__ h,
    const float* __restrict__ Wir, const float* __restrict__ bir,
    const float* __restrict__ Wiz, const float* __restrict__ biz,
    const float* __restrict__ Win, const float* __restrict__ bin,
    const float* __restrict__ Whr, const float* __restrict__ Whz,
    const float* __restrict__ Whn, const float* __restrict__ bhn,
    float* __restrict__ hnew)
{
    const int R = 16;
    __shared__ float as_[R][MSG];
    __shared__ float hs[R][HIDDEN];
    int i0 = blockIdx.x * R;
    int t = threadIdx.x;  // 256
    int j = t;

    for (int l = t; l < R * MSG; l += 256) {
        int r = l >> 7, c = l & 127;
        as_[r][c] = att[(size_t)(i0 + r) * MSG + c];
    }
    for (int l = t; l < R * HIDDEN; l += 256) {
        int r = l >> 8, c = l & 255;
        hs[r][c] = h[(size_t)(i0 + r) * HIDDEN + c];
    }
    __syncthreads();

    float ar[R], az[R], an[R], hn[R];
#pragma unroll
    for (int r = 0; r < R; r++) { ar[r] = 0.f; az[r] = 0.f; an[r] = 0.f; hn[r] = 0.f; }

    for (int k = 0; k < MSG; k++) {
        float wr = Wir[(size_t)k * HIDDEN + j];
        float wz = Wiz[(size_t)k * HIDDEN + j];
        float wn = Win[(size_t)k * HIDDEN + j];
#pragma unroll
        for (int r = 0; r < R; r++) {
            float a = as_[r][k];
            ar[r] += a * wr; az[r] += a * wz; an[r] += a * wn;
        }
    }
    for (int k = 0; k < HIDDEN; k++) {
        float wr = Whr[(size_t)k * HIDDEN + j];
        float wz = Whz[(size_t)k * HIDDEN + j];
        float wn = Whn[(size_t)k * HIDDEN + j];
#pragma unroll
        for (int r = 0; r < R; r++) {
            float hv = hs[r][k];
            ar[r] += hv * wr; az[r] += hv * wz; hn[r] += hv * wn;
        }
    }

    float br = bir[j], bz = biz[j], bn = bin[j], bh = bhn[j];
#pragma unroll
    for (int r = 0; r < R; r++) {
        float rr = 1.f / (1.f + __expf(-(ar[r] + br)));
        float zz = 1.f / (1.f + __expf(-(az[r] + bz)));
        float cand = tanhf(an[r] + bn + rr * (hn[r] + bh));
        hnew[(size_t)(i0 + r) * HIDDEN + j] = (1.f - zz) * cand + zz * hs[r][j];
    }
}

// ---------------- launch ------------------------------------------------------
extern "C" void kernel_launch(void* const* d_in, const int* in_sizes, int n_in,
                              void* d_out, int out_size, void* d_ws, size_t ws_size,
                              hipStream_t stream)
{
    const float* h     = (const float*)d_in[0];
    const float* W_msg = (const float*)d_in[1];
    const float* b_msg = (const float*)d_in[2];
    const float* W_key = (const float*)d_in[3];
    const float* b_key = (const float*)d_in[4];
    const float* W_qry = (const float*)d_in[5];
    const float* b_qry = (const float*)d_in[6];
    const float* Wi_r  = (const float*)d_in[7];
    const float* bi_r  = (const float*)d_in[8];
    const float* Wi_z  = (const float*)d_in[9];
    const float* bi_z  = (const float*)d_in[10];
    const float* Wi_n  = (const float*)d_in[11];
    const float* bi_n  = (const float*)d_in[12];
    const float* Wh_r  = (const float*)d_in[13];
    const float* Wh_z  = (const float*)d_in[14];
    const float* Wh_n  = (const float*)d_in[15];
    const float* bh_n  = (const float*)d_in[16];

    float* out  = (float*)d_out;
    float* hnew = out;                                   // [8192,256]
    float* P    = out + (size_t)N_AGENTS * HIDDEN;       // attn region [8192,8192]

    float* ws     = (float*)d_ws;
    float* rowsum = ws;                                  // 8192 f32
    float* att    = ws + N_AGENTS;                       // 8192*128 f32
    short* sbase  = (short*)(att + (size_t)N_AGENTS * MSG);
    short* msgTb  = sbase;                                // 128*8192 bf16
    short* qh     = msgTb + (size_t)MSG * N_AGENTS;       // 8192*64
    short* ql     = qh + (size_t)N_AGENTS * KEYD;
    short* kh     = ql + (size_t)N_AGENTS * KEYD;
    short* kl     = kh + (size_t)N_AGENTS * KEYD;

    // zero rowsum + attended accumulator
    hipMemsetAsync(d_ws, 0, (size_t)(N_AGENTS + (size_t)N_AGENTS * MSG) * sizeof(float), stream);

    proj_kernel<<<N_AGENTS / 16, 256, 0, stream>>>(h, W_msg, b_msg, W_key, b_key,
                                                   W_qry, b_qry, msgTb, qh, ql, kh, kl);

    score_kernel<<<dim3(N_AGENTS / 256, N_AGENTS / 64), 256, 0, stream>>>(qh, ql, kh, kl, P, rowsum);

    attend_kernel<<<dim3(KSPLIT, N_AGENTS / 64), 256, 0, stream>>>(msgTb, rowsum, P, att);

    gru_kernel<<<N_AGENTS / 16, 256, 0, stream>>>(att, h, Wi_r, bi_r, Wi_z, bi_z,
                                                  Wi_n, bi_n, Wh_r, Wh_z, Wh_n, bh_n, hnew);
}